// Round 4
// baseline (927.145 us; speedup 1.0000x reference)
//
#include <hip/hip_runtime.h>
#include <stddef.h>

// Problem constants (match reference setup_inputs)
constexpr int N_NODES = 200000;
constexpr int N_EDGES = 200000;
constexpr int N_GRAPHS = 128;
constexpr int IN_F = 256;
constexpr int HID_F = 128;
constexpr int OUT_F = 128;
constexpr int OUT_W = OUT_F + HID_F; // 256 output cols per graph

typedef __attribute__((ext_vector_type(8))) short short8;   // bf16x8 MFMA A/B frag
typedef __attribute__((ext_vector_type(4))) float float4v;  // fp32x4 MFMA C/D frag

__device__ __forceinline__ short f2bf(float f) {
    union { float f; unsigned u; } v; v.f = f;
    unsigned r = v.u + 0x7fffu + ((v.u >> 16) & 1u);  // RNE
    return (short)(r >> 16);
}

// ---------------- small utility kernels ----------------

__global__ void fill1_kernel(float* __restrict__ p, int n) {
    int i = blockIdx.x * blockDim.x + threadIdx.x;
    if (i < n) p[i] = 1.0f;
}

// deg[d] += 1 (float) and cntin[d] += 1 (int) per edge
__global__ void edge_prep_kernel(const int* __restrict__ dst, float* __restrict__ deg,
                                 int* __restrict__ cntin, int E) {
    int e = blockIdx.x * blockDim.x + threadIdx.x;
    if (e < E) {
        int d = dst[e];
        atomicAdd(&deg[d], 1.0f);
        atomicAdd(&cntin[d], 1);
    }
}

// deg -> rsqrt(deg) in place
__global__ void rsqrt_kernel(float* __restrict__ p, int n) {
    int i = blockIdx.x * blockDim.x + threadIdx.x;
    if (i < n) p[i] = rsqrtf(p[i]);
}

// Exclusive prefix scan over cnt[0..n) -> rp[0..n], and cursor copy cur[i]=rp[i].
// One block, 1024 threads. cnt may alias cur (read index i before writing index i,
// phases separated by __syncthreads).
__global__ __launch_bounds__(1024) void scan_kernel(const int* __restrict__ cnt,
                                                    int* __restrict__ rp,
                                                    int* __restrict__ cur, int n) {
    __shared__ int part[1024];
    int t = threadIdx.x;
    int chunk = (n + 1023) / 1024;
    int lo = t * chunk, hi = min(n, lo + chunk);
    int s = 0;
    for (int i = lo; i < hi; ++i) s += cnt[i];
    part[t] = s;
    __syncthreads();
    for (int ofs = 1; ofs < 1024; ofs <<= 1) {
        int v = (t >= ofs) ? part[t - ofs] : 0;
        __syncthreads();
        part[t] += v;
        __syncthreads();
    }
    int base = (t == 0) ? 0 : part[t - 1];
    for (int i = lo; i < hi; ++i) {
        int c = cnt[i];
        rp[i] = base;
        cur[i] = base;
        base += c;
    }
    if (t == 1023) rp[n] = part[1023];
}

// adj[pos] = src[e], bucketed by dst (CSR-by-dst). Order within a row arbitrary.
__global__ void bucket_kernel(const int* __restrict__ src, const int* __restrict__ dst,
                              int* __restrict__ cur, int* __restrict__ adj, int E) {
    int e = blockIdx.x * blockDim.x + threadIdx.x;
    if (e < E) {
        int pos = atomicAdd(&cur[dst[e]], 1);
        adj[pos] = src[e];
    }
}

// batch is SORTED: segment bounds by binary search (R1 post-mortem: atomics were 582us)
__global__ void bounds_kernel(const int* __restrict__ batch, int* __restrict__ start,
                              int* __restrict__ cnt, int n, int G) {
    __shared__ int s_start[N_GRAPHS + 1];
    int g = threadIdx.x;
    if (g < G) {
        int lo = 0, hi = n;
        while (lo < hi) {
            int mid = (lo + hi) >> 1;
            if (batch[mid] < g) lo = mid + 1; else hi = mid;
        }
        s_start[g] = lo;
        if (g == 0) s_start[G] = n;
    }
    __syncthreads();
    if (g < G) {
        start[g] = s_start[g];
        cnt[g] = s_start[g + 1] - s_start[g];
    }
}

// Bt[n*K + k] = bf16(W[k*128 + n]) : pre-transpose weights into MFMA-B layout.
__global__ void transpose_w_kernel(const float* __restrict__ W, short* __restrict__ Bt, int K) {
    int k = blockIdx.x;
    int n = threadIdx.x;
    Bt[(size_t)n * K + k] = f2bf(W[(size_t)k * 128 + n]);
}

// rootlin[g,f] = sum_k relu(x[root_index[g],k]) * W2[(HID_F+k)*OUT_F + f]
__global__ void rootlin_kernel(const float* __restrict__ x, const int* __restrict__ root_index,
                               const float* __restrict__ W2, float* __restrict__ rootlin)
{
    int g = blockIdx.x;
    int f = threadIdx.x; // OUT_F threads
    int r = root_index[g];
    const float* xr = x + (size_t)r * IN_F;
    float acc = 0.f;
    for (int k = 0; k < IN_F; ++k) {
        float xv = fmaxf(xr[k], 0.f);
        acc += xv * W2[(size_t)(HID_F + k) * OUT_F + f];
    }
    rootlin[(size_t)g * OUT_F + f] = acc;
}

// ---------------- bf16 MFMA GEMM ----------------
// out[M,128] = op(A)[M,KTOT] @ B[KTOT,128], epilogue v = dinv[row]*(acc [+ rootlin]).
// GATHER (conv2 only, KTOT==128): A-element for row d, col k is
//   relu(dinv[d]*(hs1[d,k] + sum_{in-edges} hs1[adj,k]) + bvec[k])
// i.e. conv1's aggregation is pulled on the fly via CSR (rp/adj) — no scatter pass,
// no atomics, no agg buffer (R3 post-mortem: scatter phase was ~40% of kernel time).
template<int KTOT, bool GATHER, bool ADDROOT>
__global__ __launch_bounds__(256) void mfma_gemm_kernel(
    const float* __restrict__ A, const short* __restrict__ Bt,
    float* __restrict__ outp,
    const float* __restrict__ dinv, const float* __restrict__ bvec,
    const float* __restrict__ rootlin, const int* __restrict__ batch,
    const int* __restrict__ rp, const int* __restrict__ adj)
{
    // stride 136 shorts = 272B: bank stride 68 == 4 mod 32 -> 2-way conflicts only (free, m136)
    __shared__ __align__(16) short As[64][136];
    __shared__ __align__(16) short Bs[128][136];

    const int tid = threadIdx.x;
    const int wave = tid >> 6;
    const int lane = tid & 63;
    const int quad = lane >> 4;
    const int l16  = lane & 15;
    const int row0 = blockIdx.x * 64;

    float4v acc[8];
    #pragma unroll
    for (int c = 0; c < 8; ++c) acc[c] = (float4v){0.f, 0.f, 0.f, 0.f};

    // A staging: 4 threads per row; thread covers cols {ac8+32*jj .. +7}, jj=0..3
    const int arow = tid >> 2;
    const int ac8 = (tid & 3) * 8;
    // B staging: thread -> (n, 64-k half)
    const int bn = tid >> 1;
    const int bk = (tid & 1) * 64;

    for (int kb = 0; kb < KTOT / 128; ++kb) {
        // stage B chunk: Bs[n][k] = Bt[n][kb*128 + k]
        {
            const short* bp = Bt + (size_t)bn * KTOT + kb * 128 + bk;
            #pragma unroll
            for (int j = 0; j < 8; ++j)
                *(short8*)&Bs[bn][bk + 8 * j] = *(const short8*)(bp + 8 * j);
        }
        if (GATHER) {
            // conv1 aggregation pulled via CSR; KTOT==128 so kb==0
            const int row = row0 + arow;
            float4 s0[4], s1[4];
            const float* hp = A + (size_t)row * 128 + ac8;
            #pragma unroll
            for (int jj = 0; jj < 4; ++jj) {
                s0[jj] = *(const float4*)(hp + 32 * jj);
                s1[jj] = *(const float4*)(hp + 32 * jj + 4);
            }
            int e0 = rp[row], e1 = rp[row + 1];
            for (int e = e0; e < e1; ++e) {
                const float* q = A + (size_t)adj[e] * 128 + ac8;
                #pragma unroll
                for (int jj = 0; jj < 4; ++jj) {
                    float4 a = *(const float4*)(q + 32 * jj);
                    float4 b = *(const float4*)(q + 32 * jj + 4);
                    s0[jj].x += a.x; s0[jj].y += a.y; s0[jj].z += a.z; s0[jj].w += a.w;
                    s1[jj].x += b.x; s1[jj].y += b.y; s1[jj].z += b.z; s1[jj].w += b.w;
                }
            }
            float asc = dinv[row];
            #pragma unroll
            for (int jj = 0; jj < 4; ++jj) {
                const float* bv = bvec + ac8 + 32 * jj;
                short8 s;
                s[0] = f2bf(fmaxf(asc * s0[jj].x + bv[0], 0.f));
                s[1] = f2bf(fmaxf(asc * s0[jj].y + bv[1], 0.f));
                s[2] = f2bf(fmaxf(asc * s0[jj].z + bv[2], 0.f));
                s[3] = f2bf(fmaxf(asc * s0[jj].w + bv[3], 0.f));
                s[4] = f2bf(fmaxf(asc * s1[jj].x + bv[4], 0.f));
                s[5] = f2bf(fmaxf(asc * s1[jj].y + bv[5], 0.f));
                s[6] = f2bf(fmaxf(asc * s1[jj].z + bv[6], 0.f));
                s[7] = f2bf(fmaxf(asc * s1[jj].w + bv[7], 0.f));
                *(short8*)&As[arow][ac8 + 32 * jj] = s;
            }
        } else {
            const float* ap = A + (size_t)(row0 + arow) * KTOT + kb * 128 + ac8;
            #pragma unroll
            for (int jj = 0; jj < 4; ++jj) {
                float4 f0 = *(const float4*)(ap + 32 * jj);
                float4 f1 = *(const float4*)(ap + 32 * jj + 4);
                short8 s;
                s[0] = f2bf(f0.x); s[1] = f2bf(f0.y); s[2] = f2bf(f0.z); s[3] = f2bf(f0.w);
                s[4] = f2bf(f1.x); s[5] = f2bf(f1.y); s[6] = f2bf(f1.z); s[7] = f2bf(f1.w);
                *(short8*)&As[arow][ac8 + 32 * jj] = s;
            }
        }
        __syncthreads();
        #pragma unroll
        for (int ks = 0; ks < 4; ++ks) {
            // A frag: A[m=l16][k=ks*32+quad*8+j]  (m89-verified layout)
            short8 af = *(const short8*)&As[wave * 16 + l16][ks * 32 + quad * 8];
            #pragma unroll
            for (int c = 0; c < 8; ++c) {
                // B frag: B[k=ks*32+quad*8+j][n=c*16+l16]
                short8 bf = *(const short8*)&Bs[c * 16 + l16][ks * 32 + quad * 8];
                acc[c] = __builtin_amdgcn_mfma_f32_16x16x32_bf16(af, bf, acc[c], 0, 0, 0);
            }
        }
        __syncthreads();
    }

    // epilogue: D[row=quad*4+r][col=c*16+l16] (m89-verified C/D layout)
    #pragma unroll
    for (int r = 0; r < 4; ++r) {
        int row = row0 + wave * 16 + quad * 4 + r;
        float di = dinv[row];
        const float* rl = nullptr;
        if (ADDROOT) rl = rootlin + (size_t)batch[row] * 128;
        #pragma unroll
        for (int c = 0; c < 8; ++c) {
            int col = c * 16 + l16;
            float v = acc[c][r];
            if (ADDROOT) v += rl[col];
            outp[(size_t)row * 128 + col] = v * di;
        }
    }
}

// out[g,0:128]   = (1/n) sum_seg relu(dinv[i]*(hs2[i]+sum_in hs2[adj]) + b2)   (pull-mode conv2)
// out[g,128:256] = n>0 ? dinv[r]*(hs1[r]+sum_in hs1[adj]) + b1 : 0             (x2[root] on the fly)
// grid (G, chunks) x 128 threads; out pre-zeroed.
__global__ void mean_kernel(const float* __restrict__ hs2, const float* __restrict__ hs1,
                            const float* __restrict__ dinv, const float* __restrict__ b1v,
                            const float* __restrict__ b2v, const int* __restrict__ root_index,
                            const int* __restrict__ cnt, const int* __restrict__ start,
                            const int* __restrict__ rp, const int* __restrict__ adj,
                            float* __restrict__ out, int chunks)
{
    int g = blockIdx.x;
    int c = blockIdx.y;
    int f = threadIdx.x; // 128
    int s = start[g], n = cnt[g];
    int per = (n + chunks - 1) / chunks;
    int lo = s + c * per;
    int hi = min(s + n, lo + per);
    float bb = b2v[f];
    float accv = 0.f;
    for (int i = lo; i < hi; ++i) {
        float v = hs2[(size_t)i * 128 + f];
        int e0 = rp[i], e1 = rp[i + 1];
        for (int e = e0; e < e1; ++e)
            v += hs2[(size_t)adj[e] * 128 + f];
        accv += fmaxf(dinv[i] * v + bb, 0.f);
    }
    if (hi > lo)
        atomicAdd(&out[(size_t)g * OUT_W + f], accv / (float)max(n, 1));
    if (c == 0) {
        int r = root_index[g];
        float v = 0.f;
        if (n > 0) {
            v = hs1[(size_t)r * 128 + f];
            int e0 = rp[r], e1 = rp[r + 1];
            for (int e = e0; e < e1; ++e)
                v += hs1[(size_t)adj[e] * 128 + f];
            v = dinv[r] * v + b1v[f];
        }
        out[(size_t)g * OUT_W + HID_F + f] = v;
    }
}

// ---------------- launch ----------------

static inline size_t align_up(size_t x, size_t a) { return (x + a - 1) / a * a; }

extern "C" void kernel_launch(void* const* d_in, const int* in_sizes, int n_in,
                              void* d_out, int out_size, void* d_ws, size_t ws_size,
                              hipStream_t stream) {
    const float* x = (const float*)d_in[0];
    const int* ei = (const int*)d_in[1];
    const int* batch = (const int*)d_in[2];
    const int* root = (const int*)d_in[3];
    const float* W1 = (const float*)d_in[4];
    const float* b1 = (const float*)d_in[5];
    const float* W2 = (const float*)d_in[6];
    const float* b2 = (const float*)d_in[7];
    float* out = (float*)d_out;

    const int* src = ei;
    const int* dst = ei + N_EDGES;

    // workspace carve-up
    char* ws = (char*)d_ws;
    size_t off = 0;
    const size_t NB = (size_t)N_NODES * 128 * sizeof(float); // 102.4 MB

    float* dinv = (float*)(ws + off);    off = align_up(off + (size_t)N_NODES * sizeof(float), 256);
    int* cnt = (int*)(ws + off);         off = align_up(off + N_GRAPHS * sizeof(int), 256);
    int* startv = (int*)(ws + off);      off = align_up(off + N_GRAPHS * sizeof(int), 256);
    float* rootlin = (float*)(ws + off); off = align_up(off + (size_t)N_GRAPHS * OUT_F * sizeof(float), 256);
    short* Bt1 = (short*)(ws + off);     off = align_up(off + (size_t)128 * IN_F * sizeof(short), 256);
    short* Bt2 = (short*)(ws + off);     off = align_up(off + (size_t)128 * HID_F * sizeof(short), 256);
    int* rowptr = (int*)(ws + off);      off = align_up(off + (size_t)(N_NODES + 1) * sizeof(int), 256);
    int* cursor = (int*)(ws + off);      off = align_up(off + (size_t)N_NODES * sizeof(int), 256);
    int* adj = (int*)(ws + off);         off = align_up(off + (size_t)N_EDGES * sizeof(int), 256);
    float* hs1 = (float*)(ws + off);     off = align_up(off + NB, 256);
    float* hs2 = (float*)(ws + off);     off = align_up(off + NB, 256);
    (void)ws_size; (void)n_in; (void)in_sizes; (void)out_size;

    // degree (with self loop) + in-degree counts -> CSR-by-dst; dinv = rsqrt(deg)
    fill1_kernel<<<(N_NODES + 255) / 256, 256, 0, stream>>>(dinv, N_NODES);
    hipMemsetAsync(cursor, 0, (size_t)N_NODES * sizeof(int), stream);
    edge_prep_kernel<<<(N_EDGES + 255) / 256, 256, 0, stream>>>(dst, dinv, cursor, N_EDGES);
    rsqrt_kernel<<<(N_NODES + 255) / 256, 256, 0, stream>>>(dinv, N_NODES);
    scan_kernel<<<1, 1024, 0, stream>>>(cursor, rowptr, cursor, N_NODES);
    bucket_kernel<<<(N_EDGES + 255) / 256, 256, 0, stream>>>(src, dst, cursor, adj, N_EDGES);
    bounds_kernel<<<1, N_GRAPHS, 0, stream>>>(batch, startv, cnt, N_NODES, N_GRAPHS);

    // weight pre-transpose to bf16 [n][k]; rootlin from raw x
    transpose_w_kernel<<<IN_F, 128, 0, stream>>>(W1, Bt1, IN_F);
    transpose_w_kernel<<<HID_F, 128, 0, stream>>>(W2, Bt2, HID_F); // first 128 rows of W2
    rootlin_kernel<<<N_GRAPHS, OUT_F, 0, stream>>>(x, root, W2, rootlin);

    // conv1 linear: hs1 = dinv .* (x @ W1)
    mfma_gemm_kernel<IN_F, false, false><<<N_NODES / 64, 256, 0, stream>>>(
        x, Bt1, hs1, dinv, nullptr, nullptr, nullptr, nullptr, nullptr);

    // conv2 linear, pulling conv1 aggregation via CSR in the A-staging:
    // hs2 = dinv .* ( relu(dinv.*(hs1 + gather) + b1) @ W2[0:128] + rootlin[batch] )
    mfma_gemm_kernel<HID_F, true, true><<<N_NODES / 64, 256, 0, stream>>>(
        hs1, Bt2, hs2, dinv, b1, rootlin, batch, rowptr, adj);

    // fused conv2-aggregation + relu + graph mean + root gather
    hipMemsetAsync(out, 0, (size_t)N_GRAPHS * OUT_W * sizeof(float), stream);
    dim3 mg(N_GRAPHS, 32);
    mean_kernel<<<mg, 128, 0, stream>>>(hs2, hs1, dinv, b1, b2, root, cnt, startv,
                                        rowptr, adj, out, 32);
}

// Round 5
// 475.408 us; speedup vs baseline: 1.9502x; 1.9502x over previous
//
#include <hip/hip_runtime.h>
#include <stddef.h>

// Problem constants (match reference setup_inputs)
constexpr int N_NODES = 200000;
constexpr int N_EDGES = 200000;
constexpr int N_GRAPHS = 128;
constexpr int IN_F = 256;
constexpr int HID_F = 128;
constexpr int OUT_F = 128;
constexpr int OUT_W = OUT_F + HID_F; // 256 output cols per graph
constexpr int SCAN_NB = (N_NODES + 1023) / 1024; // 196 blocks

typedef __attribute__((ext_vector_type(8))) short short8;   // bf16x8 MFMA A/B frag
typedef __attribute__((ext_vector_type(4))) float float4v;  // fp32x4 MFMA C/D frag

__device__ __forceinline__ short f2bf(float f) {
    union { float f; unsigned u; } v; v.f = f;
    unsigned r = v.u + 0x7fffu + ((v.u >> 16) & 1u);  // RNE
    return (short)(r >> 16);
}

// ---------------- small utility kernels ----------------

// in-degree counts (int) per edge
__global__ void edge_prep_kernel(const int* __restrict__ dst, int* __restrict__ cntin, int E) {
    int e = blockIdx.x * blockDim.x + threadIdx.x;
    if (e < E) atomicAdd(&cntin[dst[e]], 1);
}

// dinv[i] = rsqrt(1 + indeg[i])  (self-loop degree), from int counts
__global__ void dinv_kernel(const int* __restrict__ cntin, float* __restrict__ dinv, int n) {
    int i = blockIdx.x * blockDim.x + threadIdx.x;
    if (i < n) dinv[i] = rsqrtf(1.0f + (float)cntin[i]);
}

// ---- hierarchical exclusive scan (R4 post-mortem: single-block scan was 465us,
//      1 CU busy, latency-bound; 3-phase version is fully parallel) ----

// phase 1: partial[b] = sum of cnt in block b's 1024-range
__global__ __launch_bounds__(1024) void scan_reduce_kernel(const int* __restrict__ cnt,
                                                           int* __restrict__ partial, int n) {
    __shared__ int sm[1024];
    int t = threadIdx.x;
    int i = blockIdx.x * 1024 + t;
    sm[t] = (i < n) ? cnt[i] : 0;
    __syncthreads();
    for (int ofs = 512; ofs > 0; ofs >>= 1) {
        if (t < ofs) sm[t] += sm[t + ofs];
        __syncthreads();
    }
    if (t == 0) partial[blockIdx.x] = sm[0];
}

// phase 2: partial -> exclusive bases, in place (nb <= 256), one block of 256
__global__ void scan_base_kernel(int* __restrict__ partial, int nb) {
    __shared__ int sm[256];
    int t = threadIdx.x;
    sm[t] = (t < nb) ? partial[t] : 0;
    __syncthreads();
    for (int ofs = 1; ofs < 256; ofs <<= 1) {
        int v = (t >= ofs) ? sm[t - ofs] : 0;
        __syncthreads();
        sm[t] += v;
        __syncthreads();
    }
    if (t < nb) partial[t] = (t == 0) ? 0 : sm[t - 1];
}

// phase 3: local Hillis-Steele scan + base -> rp[i], cur[i]; last element writes rp[n].
// cnt may alias cur: each thread reads cnt[i] before writing cur[i] (same thread/index).
__global__ __launch_bounds__(1024) void scan_final_kernel(const int* __restrict__ cnt,
                                                          const int* __restrict__ partial,
                                                          int* __restrict__ rp,
                                                          int* __restrict__ cur, int n) {
    __shared__ int sm[1024];
    int t = threadIdx.x;
    int i = blockIdx.x * 1024 + t;
    int v = (i < n) ? cnt[i] : 0;
    sm[t] = v;
    __syncthreads();
    for (int ofs = 1; ofs < 1024; ofs <<= 1) {
        int u = (t >= ofs) ? sm[t - ofs] : 0;
        __syncthreads();
        sm[t] += u;
        __syncthreads();
    }
    int base = partial[blockIdx.x];
    if (i < n) {
        int ex = base + sm[t] - v; // exclusive
        rp[i] = ex;
        cur[i] = ex;
        if (i == n - 1) rp[n] = ex + v;
    }
}

// adj[pos] = src[e], bucketed by dst (CSR-by-dst). Order within a row arbitrary.
__global__ void bucket_kernel(const int* __restrict__ src, const int* __restrict__ dst,
                              int* __restrict__ cur, int* __restrict__ adj, int E) {
    int e = blockIdx.x * blockDim.x + threadIdx.x;
    if (e < E) {
        int pos = atomicAdd(&cur[dst[e]], 1);
        adj[pos] = src[e];
    }
}

// batch is SORTED: segment bounds by binary search (R1 post-mortem: atomics were 582us)
__global__ void bounds_kernel(const int* __restrict__ batch, int* __restrict__ start,
                              int* __restrict__ cnt, int n, int G) {
    __shared__ int s_start[N_GRAPHS + 1];
    int g = threadIdx.x;
    if (g < G) {
        int lo = 0, hi = n;
        while (lo < hi) {
            int mid = (lo + hi) >> 1;
            if (batch[mid] < g) lo = mid + 1; else hi = mid;
        }
        s_start[g] = lo;
        if (g == 0) s_start[G] = n;
    }
    __syncthreads();
    if (g < G) {
        start[g] = s_start[g];
        cnt[g] = s_start[g + 1] - s_start[g];
    }
}

// Bt[n*K + k] = bf16(W[k*128 + n]) : pre-transpose weights into MFMA-B layout.
__global__ void transpose_w_kernel(const float* __restrict__ W, short* __restrict__ Bt, int K) {
    int k = blockIdx.x;
    int n = threadIdx.x;
    Bt[(size_t)n * K + k] = f2bf(W[(size_t)k * 128 + n]);
}

// rootlin[g,f] = sum_k relu(x[root_index[g],k]) * W2[(HID_F+k)*OUT_F + f]
__global__ void rootlin_kernel(const float* __restrict__ x, const int* __restrict__ root_index,
                               const float* __restrict__ W2, float* __restrict__ rootlin)
{
    int g = blockIdx.x;
    int f = threadIdx.x; // OUT_F threads
    int r = root_index[g];
    const float* xr = x + (size_t)r * IN_F;
    float acc = 0.f;
    for (int k = 0; k < IN_F; ++k) {
        float xv = fmaxf(xr[k], 0.f);
        acc += xv * W2[(size_t)(HID_F + k) * OUT_F + f];
    }
    rootlin[(size_t)g * OUT_F + f] = acc;
}

// ---------------- bf16 MFMA GEMM ----------------
// out[M,128] = op(A)[M,KTOT] @ B[KTOT,128], epilogue v = dinv[row]*(acc [+ rootlin]).
// GATHER (conv2 only, KTOT==128): A-element for row d, col k is
//   relu(dinv[d]*(hs1[d,k] + sum_{in-edges} hs1[adj,k]) + bvec[k])
// i.e. conv1's aggregation is pulled on the fly via CSR (rp/adj) — no scatter pass,
// no atomics, no agg buffer.
template<int KTOT, bool GATHER, bool ADDROOT>
__global__ __launch_bounds__(256) void mfma_gemm_kernel(
    const float* __restrict__ A, const short* __restrict__ Bt,
    float* __restrict__ outp,
    const float* __restrict__ dinv, const float* __restrict__ bvec,
    const float* __restrict__ rootlin, const int* __restrict__ batch,
    const int* __restrict__ rp, const int* __restrict__ adj)
{
    // stride 136 shorts = 272B: bank stride 68 == 4 mod 32 -> 2-way conflicts only (free, m136)
    __shared__ __align__(16) short As[64][136];
    __shared__ __align__(16) short Bs[128][136];

    const int tid = threadIdx.x;
    const int wave = tid >> 6;
    const int lane = tid & 63;
    const int quad = lane >> 4;
    const int l16  = lane & 15;
    const int row0 = blockIdx.x * 64;

    float4v acc[8];
    #pragma unroll
    for (int c = 0; c < 8; ++c) acc[c] = (float4v){0.f, 0.f, 0.f, 0.f};

    // A staging: 4 threads per row; thread covers cols {ac8+32*jj .. +7}, jj=0..3
    const int arow = tid >> 2;
    const int ac8 = (tid & 3) * 8;
    // B staging: thread -> (n, 64-k half)
    const int bn = tid >> 1;
    const int bk = (tid & 1) * 64;

    for (int kb = 0; kb < KTOT / 128; ++kb) {
        // stage B chunk: Bs[n][k] = Bt[n][kb*128 + k]
        {
            const short* bp = Bt + (size_t)bn * KTOT + kb * 128 + bk;
            #pragma unroll
            for (int j = 0; j < 8; ++j)
                *(short8*)&Bs[bn][bk + 8 * j] = *(const short8*)(bp + 8 * j);
        }
        if (GATHER) {
            // conv1 aggregation pulled via CSR; KTOT==128 so kb==0
            const int row = row0 + arow;
            float4 s0[4], s1[4];
            const float* hp = A + (size_t)row * 128 + ac8;
            #pragma unroll
            for (int jj = 0; jj < 4; ++jj) {
                s0[jj] = *(const float4*)(hp + 32 * jj);
                s1[jj] = *(const float4*)(hp + 32 * jj + 4);
            }
            int e0 = rp[row], e1 = rp[row + 1];
            for (int e = e0; e < e1; ++e) {
                const float* q = A + (size_t)adj[e] * 128 + ac8;
                #pragma unroll
                for (int jj = 0; jj < 4; ++jj) {
                    float4 a = *(const float4*)(q + 32 * jj);
                    float4 b = *(const float4*)(q + 32 * jj + 4);
                    s0[jj].x += a.x; s0[jj].y += a.y; s0[jj].z += a.z; s0[jj].w += a.w;
                    s1[jj].x += b.x; s1[jj].y += b.y; s1[jj].z += b.z; s1[jj].w += b.w;
                }
            }
            float asc = dinv[row];
            #pragma unroll
            for (int jj = 0; jj < 4; ++jj) {
                const float* bv = bvec + ac8 + 32 * jj;
                short8 s;
                s[0] = f2bf(fmaxf(asc * s0[jj].x + bv[0], 0.f));
                s[1] = f2bf(fmaxf(asc * s0[jj].y + bv[1], 0.f));
                s[2] = f2bf(fmaxf(asc * s0[jj].z + bv[2], 0.f));
                s[3] = f2bf(fmaxf(asc * s0[jj].w + bv[3], 0.f));
                s[4] = f2bf(fmaxf(asc * s1[jj].x + bv[4], 0.f));
                s[5] = f2bf(fmaxf(asc * s1[jj].y + bv[5], 0.f));
                s[6] = f2bf(fmaxf(asc * s1[jj].z + bv[6], 0.f));
                s[7] = f2bf(fmaxf(asc * s1[jj].w + bv[7], 0.f));
                *(short8*)&As[arow][ac8 + 32 * jj] = s;
            }
        } else {
            const float* ap = A + (size_t)(row0 + arow) * KTOT + kb * 128 + ac8;
            #pragma unroll
            for (int jj = 0; jj < 4; ++jj) {
                float4 f0 = *(const float4*)(ap + 32 * jj);
                float4 f1 = *(const float4*)(ap + 32 * jj + 4);
                short8 s;
                s[0] = f2bf(f0.x); s[1] = f2bf(f0.y); s[2] = f2bf(f0.z); s[3] = f2bf(f0.w);
                s[4] = f2bf(f1.x); s[5] = f2bf(f1.y); s[6] = f2bf(f1.z); s[7] = f2bf(f1.w);
                *(short8*)&As[arow][ac8 + 32 * jj] = s;
            }
        }
        __syncthreads();
        #pragma unroll
        for (int ks = 0; ks < 4; ++ks) {
            // A frag: A[m=l16][k=ks*32+quad*8+j]  (m89-verified layout)
            short8 af = *(const short8*)&As[wave * 16 + l16][ks * 32 + quad * 8];
            #pragma unroll
            for (int c = 0; c < 8; ++c) {
                // B frag: B[k=ks*32+quad*8+j][n=c*16+l16]
                short8 bf = *(const short8*)&Bs[c * 16 + l16][ks * 32 + quad * 8];
                acc[c] = __builtin_amdgcn_mfma_f32_16x16x32_bf16(af, bf, acc[c], 0, 0, 0);
            }
        }
        __syncthreads();
    }

    // epilogue: D[row=quad*4+r][col=c*16+l16] (m89-verified C/D layout)
    #pragma unroll
    for (int r = 0; r < 4; ++r) {
        int row = row0 + wave * 16 + quad * 4 + r;
        float di = dinv[row];
        const float* rl = nullptr;
        if (ADDROOT) rl = rootlin + (size_t)batch[row] * 128;
        #pragma unroll
        for (int c = 0; c < 8; ++c) {
            int col = c * 16 + l16;
            float v = acc[c][r];
            if (ADDROOT) v += rl[col];
            outp[(size_t)row * 128 + col] = v * di;
        }
    }
}

// out[g,0:128]   = (1/n) sum_seg relu(dinv[i]*(hs2[i]+sum_in hs2[adj]) + b2)   (pull-mode conv2)
// out[g,128:256] = n>0 ? dinv[r]*(hs1[r]+sum_in hs1[adj]) + b1 : 0             (x2[root] on the fly)
// grid (G, chunks) x 128 threads; out pre-zeroed.
__global__ void mean_kernel(const float* __restrict__ hs2, const float* __restrict__ hs1,
                            const float* __restrict__ dinv, const float* __restrict__ b1v,
                            const float* __restrict__ b2v, const int* __restrict__ root_index,
                            const int* __restrict__ cnt, const int* __restrict__ start,
                            const int* __restrict__ rp, const int* __restrict__ adj,
                            float* __restrict__ out, int chunks)
{
    int g = blockIdx.x;
    int c = blockIdx.y;
    int f = threadIdx.x; // 128
    int s = start[g], n = cnt[g];
    int per = (n + chunks - 1) / chunks;
    int lo = s + c * per;
    int hi = min(s + n, lo + per);
    float bb = b2v[f];
    float accv = 0.f;
    for (int i = lo; i < hi; ++i) {
        float v = hs2[(size_t)i * 128 + f];
        int e0 = rp[i], e1 = rp[i + 1];
        for (int e = e0; e < e1; ++e)
            v += hs2[(size_t)adj[e] * 128 + f];
        accv += fmaxf(dinv[i] * v + bb, 0.f);
    }
    if (hi > lo)
        atomicAdd(&out[(size_t)g * OUT_W + f], accv / (float)max(n, 1));
    if (c == 0) {
        int r = root_index[g];
        float v = 0.f;
        if (n > 0) {
            v = hs1[(size_t)r * 128 + f];
            int e0 = rp[r], e1 = rp[r + 1];
            for (int e = e0; e < e1; ++e)
                v += hs1[(size_t)adj[e] * 128 + f];
            v = dinv[r] * v + b1v[f];
        }
        out[(size_t)g * OUT_W + HID_F + f] = v;
    }
}

// ---------------- launch ----------------

static inline size_t align_up(size_t x, size_t a) { return (x + a - 1) / a * a; }

extern "C" void kernel_launch(void* const* d_in, const int* in_sizes, int n_in,
                              void* d_out, int out_size, void* d_ws, size_t ws_size,
                              hipStream_t stream) {
    const float* x = (const float*)d_in[0];
    const int* ei = (const int*)d_in[1];
    const int* batch = (const int*)d_in[2];
    const int* root = (const int*)d_in[3];
    const float* W1 = (const float*)d_in[4];
    const float* b1 = (const float*)d_in[5];
    const float* W2 = (const float*)d_in[6];
    const float* b2 = (const float*)d_in[7];
    float* out = (float*)d_out;

    const int* src = ei;
    const int* dst = ei + N_EDGES;

    // workspace carve-up
    char* ws = (char*)d_ws;
    size_t off = 0;
    const size_t NB = (size_t)N_NODES * 128 * sizeof(float); // 102.4 MB

    float* dinv = (float*)(ws + off);    off = align_up(off + (size_t)N_NODES * sizeof(float), 256);
    int* cnt = (int*)(ws + off);         off = align_up(off + N_GRAPHS * sizeof(int), 256);
    int* startv = (int*)(ws + off);      off = align_up(off + N_GRAPHS * sizeof(int), 256);
    float* rootlin = (float*)(ws + off); off = align_up(off + (size_t)N_GRAPHS * OUT_F * sizeof(float), 256);
    short* Bt1 = (short*)(ws + off);     off = align_up(off + (size_t)128 * IN_F * sizeof(short), 256);
    short* Bt2 = (short*)(ws + off);     off = align_up(off + (size_t)128 * HID_F * sizeof(short), 256);
    int* rowptr = (int*)(ws + off);      off = align_up(off + (size_t)(N_NODES + 1) * sizeof(int), 256);
    int* cursor = (int*)(ws + off);      off = align_up(off + (size_t)N_NODES * sizeof(int), 256);
    int* partial = (int*)(ws + off);     off = align_up(off + (size_t)SCAN_NB * sizeof(int), 256);
    int* adj = (int*)(ws + off);         off = align_up(off + (size_t)N_EDGES * sizeof(int), 256);
    float* hs1 = (float*)(ws + off);     off = align_up(off + NB, 256);
    float* hs2 = (float*)(ws + off);     off = align_up(off + NB, 256);
    (void)ws_size; (void)n_in; (void)in_sizes; (void)out_size;

    // in-degree -> dinv = rsqrt(1+indeg); CSR-by-dst via hierarchical scan + bucket
    hipMemsetAsync(cursor, 0, (size_t)N_NODES * sizeof(int), stream);
    edge_prep_kernel<<<(N_EDGES + 255) / 256, 256, 0, stream>>>(dst, cursor, N_EDGES);
    dinv_kernel<<<(N_NODES + 255) / 256, 256, 0, stream>>>(cursor, dinv, N_NODES);
    scan_reduce_kernel<<<SCAN_NB, 1024, 0, stream>>>(cursor, partial, N_NODES);
    scan_base_kernel<<<1, 256, 0, stream>>>(partial, SCAN_NB);
    scan_final_kernel<<<SCAN_NB, 1024, 0, stream>>>(cursor, partial, rowptr, cursor, N_NODES);
    bucket_kernel<<<(N_EDGES + 255) / 256, 256, 0, stream>>>(src, dst, cursor, adj, N_EDGES);
    bounds_kernel<<<1, N_GRAPHS, 0, stream>>>(batch, startv, cnt, N_NODES, N_GRAPHS);

    // weight pre-transpose to bf16 [n][k]; rootlin from raw x
    transpose_w_kernel<<<IN_F, 128, 0, stream>>>(W1, Bt1, IN_F);
    transpose_w_kernel<<<HID_F, 128, 0, stream>>>(W2, Bt2, HID_F); // first 128 rows of W2
    rootlin_kernel<<<N_GRAPHS, OUT_F, 0, stream>>>(x, root, W2, rootlin);

    // conv1 linear: hs1 = dinv .* (x @ W1)
    mfma_gemm_kernel<IN_F, false, false><<<N_NODES / 64, 256, 0, stream>>>(
        x, Bt1, hs1, dinv, nullptr, nullptr, nullptr, nullptr, nullptr);

    // conv2 linear, pulling conv1 aggregation via CSR in the A-staging:
    // hs2 = dinv .* ( relu(dinv.*(hs1 + gather) + b1) @ W2[0:128] + rootlin[batch] )
    mfma_gemm_kernel<HID_F, true, true><<<N_NODES / 64, 256, 0, stream>>>(
        hs1, Bt2, hs2, dinv, b1, rootlin, batch, rowptr, adj);

    // fused conv2-aggregation + relu + graph mean + root gather
    hipMemsetAsync(out, 0, (size_t)N_GRAPHS * OUT_W * sizeof(float), stream);
    dim3 mg(N_GRAPHS, 32);
    mean_kernel<<<mg, 128, 0, stream>>>(hs2, hs1, dinv, b1, b2, root, cnt, startv,
                                        rowptr, adj, out, 32);
}

// Round 6
// 456.058 us; speedup vs baseline: 2.0330x; 1.0424x over previous
//
#include <hip/hip_runtime.h>
#include <stddef.h>

// Problem constants (match reference setup_inputs)
constexpr int N_NODES = 200000;
constexpr int N_EDGES = 200000;
constexpr int N_GRAPHS = 128;
constexpr int IN_F = 256;
constexpr int HID_F = 128;
constexpr int OUT_F = 128;
constexpr int OUT_W = OUT_F + HID_F; // 256 output cols per graph
constexpr int SCAN_NB = (N_NODES + 1023) / 1024; // 196 blocks

typedef __attribute__((ext_vector_type(8))) short short8;   // bf16x8 MFMA A/B frag
typedef __attribute__((ext_vector_type(4))) float float4v;  // fp32x4 MFMA C/D frag

__device__ __forceinline__ short f2bf(float f) {
    union { float f; unsigned u; } v; v.f = f;
    unsigned r = v.u + 0x7fffu + ((v.u >> 16) & 1u);  // RNE
    return (short)(r >> 16);
}
__device__ __forceinline__ float bf2f(unsigned short s) {
    union { unsigned u; float f; } v; v.u = ((unsigned)s) << 16;
    return v.f;
}

// ---------------- small utility kernels ----------------

// in-degree counts (int) per edge
__global__ void edge_prep_kernel(const int* __restrict__ dst, int* __restrict__ cntin, int E) {
    int e = blockIdx.x * blockDim.x + threadIdx.x;
    if (e < E) atomicAdd(&cntin[dst[e]], 1);
}

// ---- hierarchical exclusive scan (R4 post-mortem: single-block scan was 465us,
//      1 CU busy, latency-bound; 3-phase version is fully parallel) ----

// phase 1: partial[b] = sum of cnt in block b's 1024-range
__global__ __launch_bounds__(1024) void scan_reduce_kernel(const int* __restrict__ cnt,
                                                           int* __restrict__ partial, int n) {
    __shared__ int sm[1024];
    int t = threadIdx.x;
    int i = blockIdx.x * 1024 + t;
    sm[t] = (i < n) ? cnt[i] : 0;
    __syncthreads();
    for (int ofs = 512; ofs > 0; ofs >>= 1) {
        if (t < ofs) sm[t] += sm[t + ofs];
        __syncthreads();
    }
    if (t == 0) partial[blockIdx.x] = sm[0];
}

// phase 2: partial -> exclusive bases, in place (nb <= 256), one block of 256
__global__ void scan_base_kernel(int* __restrict__ partial, int nb) {
    __shared__ int sm[256];
    int t = threadIdx.x;
    sm[t] = (t < nb) ? partial[t] : 0;
    __syncthreads();
    for (int ofs = 1; ofs < 256; ofs <<= 1) {
        int v = (t >= ofs) ? sm[t - ofs] : 0;
        __syncthreads();
        sm[t] += v;
        __syncthreads();
    }
    if (t < nb) partial[t] = (t == 0) ? 0 : sm[t - 1];
}

// phase 3: local Hillis-Steele scan + base -> rp[i], cur[i]; last writes rp[n].
// Also dinv[i] = rsqrt(1 + indeg[i]) (fused; saves a pass over cnt).
// cnt may alias cur: each thread reads cnt[i] before writing cur[i] (same thread/index).
__global__ __launch_bounds__(1024) void scan_final_kernel(const int* __restrict__ cnt,
                                                          const int* __restrict__ partial,
                                                          int* __restrict__ rp,
                                                          int* __restrict__ cur,
                                                          float* __restrict__ dinv, int n) {
    __shared__ int sm[1024];
    int t = threadIdx.x;
    int i = blockIdx.x * 1024 + t;
    int v = (i < n) ? cnt[i] : 0;
    sm[t] = v;
    __syncthreads();
    for (int ofs = 1; ofs < 1024; ofs <<= 1) {
        int u = (t >= ofs) ? sm[t - ofs] : 0;
        __syncthreads();
        sm[t] += u;
        __syncthreads();
    }
    int base = partial[blockIdx.x];
    if (i < n) {
        int ex = base + sm[t] - v; // exclusive
        rp[i] = ex;
        cur[i] = ex;
        dinv[i] = rsqrtf(1.0f + (float)v);
        if (i == n - 1) rp[n] = ex + v;
    }
}

// adj[pos] = src[e], bucketed by dst (CSR-by-dst). Order within a row arbitrary.
__global__ void bucket_kernel(const int* __restrict__ src, const int* __restrict__ dst,
                              int* __restrict__ cur, int* __restrict__ adj, int E) {
    int e = blockIdx.x * blockDim.x + threadIdx.x;
    if (e < E) {
        int pos = atomicAdd(&cur[dst[e]], 1);
        adj[pos] = src[e];
    }
}

// batch is SORTED: segment bounds by binary search (R1 post-mortem: atomics were 582us)
__global__ void bounds_kernel(const int* __restrict__ batch, int* __restrict__ start,
                              int* __restrict__ cnt, int n, int G) {
    __shared__ int s_start[N_GRAPHS + 1];
    int g = threadIdx.x;
    if (g < G) {
        int lo = 0, hi = n;
        while (lo < hi) {
            int mid = (lo + hi) >> 1;
            if (batch[mid] < g) lo = mid + 1; else hi = mid;
        }
        s_start[g] = lo;
        if (g == 0) s_start[G] = n;
    }
    __syncthreads();
    if (g < G) {
        start[g] = s_start[g];
        cnt[g] = s_start[g + 1] - s_start[g];
    }
}

// Both weight pre-transposes in one launch: Bt[n*K + k] = bf16(W[k*128 + n]).
__global__ void transpose_w_kernel(const float* __restrict__ W1, const float* __restrict__ W2,
                                   short* __restrict__ Bt1, short* __restrict__ Bt2) {
    int k = blockIdx.x;
    int n = threadIdx.x;
    if (k < IN_F) {
        Bt1[(size_t)n * IN_F + k] = f2bf(W1[(size_t)k * 128 + n]);
    } else {
        int kk = k - IN_F;
        Bt2[(size_t)n * HID_F + kk] = f2bf(W2[(size_t)kk * 128 + n]);
    }
}

// rootlin[g,f] = sum_k relu(x[root_index[g],k]) * W2[(HID_F+k)*OUT_F + f]
__global__ void rootlin_kernel(const float* __restrict__ x, const int* __restrict__ root_index,
                               const float* __restrict__ W2, float* __restrict__ rootlin)
{
    int g = blockIdx.x;
    int f = threadIdx.x; // OUT_F threads
    int r = root_index[g];
    const float* xr = x + (size_t)r * IN_F;
    float acc = 0.f;
    for (int k = 0; k < IN_F; ++k) {
        float xv = fmaxf(xr[k], 0.f);
        acc += xv * W2[(size_t)(HID_F + k) * OUT_F + f];
    }
    rootlin[(size_t)g * OUT_F + f] = acc;
}

// ---------------- bf16 MFMA GEMM ----------------
// out[M,128] = op(A)[M,KTOT] @ B[KTOT,128], epilogue v = dinv[row]*(acc [+ rootlin]),
// stored as bf16 (R6: intermediates are bf16-rounded for MFMA anyway; halves hs traffic).
// GATHER (conv2, KTOT==128): A is bf16 hs1; A-element for row d, col k is
//   relu(dinv[d]*(hs1[d,k] + sum_{in-edges} hs1[adj,k]) + bvec[k])  — pull-mode, no atomics.
template<int KTOT, bool GATHER, bool ADDROOT>
__global__ __launch_bounds__(256) void mfma_gemm_kernel(
    const void* __restrict__ Ap, const short* __restrict__ Bt,
    unsigned short* __restrict__ outp,
    const float* __restrict__ dinv, const float* __restrict__ bvec,
    const float* __restrict__ rootlin, const int* __restrict__ batch,
    const int* __restrict__ rp, const int* __restrict__ adj)
{
    // stride 136 shorts = 272B: bank stride 68 == 4 mod 32 -> 2-way conflicts only (free, m136)
    __shared__ __align__(16) short As[64][136];
    __shared__ __align__(16) short Bs[128][136];

    const int tid = threadIdx.x;
    const int wave = tid >> 6;
    const int lane = tid & 63;
    const int quad = lane >> 4;
    const int l16  = lane & 15;
    const int row0 = blockIdx.x * 64;

    float4v acc[8];
    #pragma unroll
    for (int c = 0; c < 8; ++c) acc[c] = (float4v){0.f, 0.f, 0.f, 0.f};

    // A staging: 4 threads per row; thread covers cols {ac8+32*jj .. +7}, jj=0..3
    const int arow = tid >> 2;
    const int ac8 = (tid & 3) * 8;
    // B staging: thread -> (n, 64-k half)
    const int bn = tid >> 1;
    const int bk = (tid & 1) * 64;

    for (int kb = 0; kb < KTOT / 128; ++kb) {
        // stage B chunk: Bs[n][k] = Bt[n][kb*128 + k]
        {
            const short* bp = Bt + (size_t)bn * KTOT + kb * 128 + bk;
            #pragma unroll
            for (int j = 0; j < 8; ++j)
                *(short8*)&Bs[bn][bk + 8 * j] = *(const short8*)(bp + 8 * j);
        }
        if (GATHER) {
            // conv1 aggregation pulled via CSR from bf16 hs1; KTOT==128 so kb==0
            const unsigned short* A = (const unsigned short*)Ap;
            const int row = row0 + arow;
            float sum[4][8];
            const unsigned short* hp = A + (size_t)row * 128 + ac8;
            #pragma unroll
            for (int jj = 0; jj < 4; ++jj) {
                short8 h = *(const short8*)(hp + 32 * jj);
                #pragma unroll
                for (int q = 0; q < 8; ++q) sum[jj][q] = bf2f((unsigned short)h[q]);
            }
            int e0 = rp[row], e1 = rp[row + 1];
            for (int e = e0; e < e1; ++e) {
                const unsigned short* qp = A + (size_t)adj[e] * 128 + ac8;
                #pragma unroll
                for (int jj = 0; jj < 4; ++jj) {
                    short8 h = *(const short8*)(qp + 32 * jj);
                    #pragma unroll
                    for (int q = 0; q < 8; ++q) sum[jj][q] += bf2f((unsigned short)h[q]);
                }
            }
            float asc = dinv[row];
            #pragma unroll
            for (int jj = 0; jj < 4; ++jj) {
                const float* bv = bvec + ac8 + 32 * jj;
                short8 s;
                #pragma unroll
                for (int q = 0; q < 8; ++q)
                    s[q] = f2bf(fmaxf(asc * sum[jj][q] + bv[q], 0.f));
                *(short8*)&As[arow][ac8 + 32 * jj] = s;
            }
        } else {
            const float* A = (const float*)Ap;
            const float* ap = A + (size_t)(row0 + arow) * KTOT + kb * 128 + ac8;
            #pragma unroll
            for (int jj = 0; jj < 4; ++jj) {
                float4 f0 = *(const float4*)(ap + 32 * jj);
                float4 f1 = *(const float4*)(ap + 32 * jj + 4);
                short8 s;
                s[0] = f2bf(f0.x); s[1] = f2bf(f0.y); s[2] = f2bf(f0.z); s[3] = f2bf(f0.w);
                s[4] = f2bf(f1.x); s[5] = f2bf(f1.y); s[6] = f2bf(f1.z); s[7] = f2bf(f1.w);
                *(short8*)&As[arow][ac8 + 32 * jj] = s;
            }
        }
        __syncthreads();
        #pragma unroll
        for (int ks = 0; ks < 4; ++ks) {
            // A frag: A[m=l16][k=ks*32+quad*8+j]  (m89-verified layout)
            short8 af = *(const short8*)&As[wave * 16 + l16][ks * 32 + quad * 8];
            #pragma unroll
            for (int c = 0; c < 8; ++c) {
                // B frag: B[k=ks*32+quad*8+j][n=c*16+l16]
                short8 bf = *(const short8*)&Bs[c * 16 + l16][ks * 32 + quad * 8];
                acc[c] = __builtin_amdgcn_mfma_f32_16x16x32_bf16(af, bf, acc[c], 0, 0, 0);
            }
        }
        __syncthreads();
    }

    // epilogue: D[row=quad*4+r][col=c*16+l16] (m89-verified C/D layout); bf16 store
    #pragma unroll
    for (int r = 0; r < 4; ++r) {
        int row = row0 + wave * 16 + quad * 4 + r;
        float di = dinv[row];
        const float* rl = nullptr;
        if (ADDROOT) rl = rootlin + (size_t)batch[row] * 128;
        #pragma unroll
        for (int c = 0; c < 8; ++c) {
            int col = c * 16 + l16;
            float v = acc[c][r];
            if (ADDROOT) v += rl[col];
            outp[(size_t)row * 128 + col] = (unsigned short)f2bf(v * di);
        }
    }
}

// out[g,0:128]   = (1/n) sum_seg relu(dinv[i]*(hs2[i]+sum_in hs2[adj]) + b2)   (pull-mode conv2)
// out[g,128:256] = n>0 ? dinv[r]*(hs1[r]+sum_in hs1[adj]) + b1 : 0             (x2[root] on the fly)
// hs1/hs2 are bf16. grid (G, chunks) x 128 threads; out pre-zeroed.
__global__ void mean_kernel(const unsigned short* __restrict__ hs2,
                            const unsigned short* __restrict__ hs1,
                            const float* __restrict__ dinv, const float* __restrict__ b1v,
                            const float* __restrict__ b2v, const int* __restrict__ root_index,
                            const int* __restrict__ cnt, const int* __restrict__ start,
                            const int* __restrict__ rp, const int* __restrict__ adj,
                            float* __restrict__ out, int chunks)
{
    int g = blockIdx.x;
    int c = blockIdx.y;
    int f = threadIdx.x; // 128
    int s = start[g], n = cnt[g];
    int per = (n + chunks - 1) / chunks;
    int lo = s + c * per;
    int hi = min(s + n, lo + per);
    float bb = b2v[f];
    float accv = 0.f;
    for (int i = lo; i < hi; ++i) {
        float v = bf2f(hs2[(size_t)i * 128 + f]);
        int e0 = rp[i], e1 = rp[i + 1];
        for (int e = e0; e < e1; ++e)
            v += bf2f(hs2[(size_t)adj[e] * 128 + f]);
        accv += fmaxf(dinv[i] * v + bb, 0.f);
    }
    if (hi > lo)
        atomicAdd(&out[(size_t)g * OUT_W + f], accv / (float)max(n, 1));
    if (c == 0) {
        int r = root_index[g];
        float v = 0.f;
        if (n > 0) {
            v = bf2f(hs1[(size_t)r * 128 + f]);
            int e0 = rp[r], e1 = rp[r + 1];
            for (int e = e0; e < e1; ++e)
                v += bf2f(hs1[(size_t)adj[e] * 128 + f]);
            v = dinv[r] * v + b1v[f];
        }
        out[(size_t)g * OUT_W + HID_F + f] = v;
    }
}

// ---------------- launch ----------------

static inline size_t align_up(size_t x, size_t a) { return (x + a - 1) / a * a; }

extern "C" void kernel_launch(void* const* d_in, const int* in_sizes, int n_in,
                              void* d_out, int out_size, void* d_ws, size_t ws_size,
                              hipStream_t stream) {
    const float* x = (const float*)d_in[0];
    const int* ei = (const int*)d_in[1];
    const int* batch = (const int*)d_in[2];
    const int* root = (const int*)d_in[3];
    const float* W1 = (const float*)d_in[4];
    const float* b1 = (const float*)d_in[5];
    const float* W2 = (const float*)d_in[6];
    const float* b2 = (const float*)d_in[7];
    float* out = (float*)d_out;

    const int* src = ei;
    const int* dst = ei + N_EDGES;

    // workspace carve-up
    char* ws = (char*)d_ws;
    size_t off = 0;
    const size_t NB16 = (size_t)N_NODES * 128 * sizeof(unsigned short); // 51.2 MB

    float* dinv = (float*)(ws + off);    off = align_up(off + (size_t)N_NODES * sizeof(float), 256);
    int* cnt = (int*)(ws + off);         off = align_up(off + N_GRAPHS * sizeof(int), 256);
    int* startv = (int*)(ws + off);      off = align_up(off + N_GRAPHS * sizeof(int), 256);
    float* rootlin = (float*)(ws + off); off = align_up(off + (size_t)N_GRAPHS * OUT_F * sizeof(float), 256);
    short* Bt1 = (short*)(ws + off);     off = align_up(off + (size_t)128 * IN_F * sizeof(short), 256);
    short* Bt2 = (short*)(ws + off);     off = align_up(off + (size_t)128 * HID_F * sizeof(short), 256);
    int* rowptr = (int*)(ws + off);      off = align_up(off + (size_t)(N_NODES + 1) * sizeof(int), 256);
    int* cursor = (int*)(ws + off);      off = align_up(off + (size_t)N_NODES * sizeof(int), 256);
    int* partial = (int*)(ws + off);     off = align_up(off + (size_t)SCAN_NB * sizeof(int), 256);
    int* adj = (int*)(ws + off);         off = align_up(off + (size_t)N_EDGES * sizeof(int), 256);
    unsigned short* hs1 = (unsigned short*)(ws + off); off = align_up(off + NB16, 256);
    unsigned short* hs2 = (unsigned short*)(ws + off); off = align_up(off + NB16, 256);
    (void)ws_size; (void)n_in; (void)in_sizes; (void)out_size;

    // in-degree -> CSR-by-dst via hierarchical scan (+ fused dinv) + bucket
    hipMemsetAsync(cursor, 0, (size_t)N_NODES * sizeof(int), stream);
    edge_prep_kernel<<<(N_EDGES + 255) / 256, 256, 0, stream>>>(dst, cursor, N_EDGES);
    scan_reduce_kernel<<<SCAN_NB, 1024, 0, stream>>>(cursor, partial, N_NODES);
    scan_base_kernel<<<1, 256, 0, stream>>>(partial, SCAN_NB);
    scan_final_kernel<<<SCAN_NB, 1024, 0, stream>>>(cursor, partial, rowptr, cursor, dinv, N_NODES);
    bucket_kernel<<<(N_EDGES + 255) / 256, 256, 0, stream>>>(src, dst, cursor, adj, N_EDGES);
    bounds_kernel<<<1, N_GRAPHS, 0, stream>>>(batch, startv, cnt, N_NODES, N_GRAPHS);

    // weight pre-transposes (one launch) + rootlin from raw x
    transpose_w_kernel<<<IN_F + HID_F, 128, 0, stream>>>(W1, W2, Bt1, Bt2);
    rootlin_kernel<<<N_GRAPHS, OUT_F, 0, stream>>>(x, root, W2, rootlin);

    // conv1 linear: hs1 = bf16( dinv .* (x @ W1) )
    mfma_gemm_kernel<IN_F, false, false><<<N_NODES / 64, 256, 0, stream>>>(
        x, Bt1, hs1, dinv, nullptr, nullptr, nullptr, nullptr, nullptr);

    // conv2 linear, pulling conv1 aggregation via CSR in the A-staging:
    // hs2 = bf16( dinv .* ( relu(dinv.*(hs1 + gather) + b1) @ W2[0:128] + rootlin[batch] ) )
    mfma_gemm_kernel<HID_F, true, true><<<N_NODES / 64, 256, 0, stream>>>(
        hs1, Bt2, hs2, dinv, b1, rootlin, batch, rowptr, adj);

    // fused conv2-aggregation + relu + graph mean + root gather
    hipMemsetAsync(out, 0, (size_t)N_GRAPHS * OUT_W * sizeof(float), stream);
    dim3 mg(N_GRAPHS, 32);
    mean_kernel<<<mg, 128, 0, stream>>>(hs2, hs1, dinv, b1, b2, root, cnt, startv,
                                        rowptr, adj, out, 32);
}